// Round 13
// baseline (74.351 us; speedup 1.0000x reference)
//
#include <hip/hip_runtime.h>
#include <hip/hip_bf16.h>
#include <hip/hip_cooperative_groups.h>

namespace cg = cooperative_groups;

#define B_    2
#define N_    2048
#define DIM_  512
#define H_    8
#define DH_   64
#define QKVW  1536          // 3*H*DH
#define BAND_ 128
#define LN_EPS 1e-5f

typedef __attribute__((ext_vector_type(8))) short bf16x8;
typedef __attribute__((ext_vector_type(4))) float f32x4;
typedef __attribute__((ext_vector_type(8))) unsigned short ushort8;

__device__ __forceinline__ float bf2f(unsigned short u) {
    union { unsigned int i; float f; } w; w.i = ((unsigned int)u) << 16; return w.f;
}
__device__ __forceinline__ unsigned short f2bf(float f) {
    __hip_bfloat16 h = __float2bfloat16(f);
    return *reinterpret_cast<unsigned short*>(&h);
}
// async global->LDS, 16B per lane; lds base wave-uniform (HW adds lane*16)
__device__ __forceinline__ void async_copy16(void* lds, const void* g) {
    __builtin_amdgcn_global_load_lds(
        (const __attribute__((address_space(1))) unsigned int*)g,
        (__attribute__((address_space(3))) unsigned int*)lds, 16, 0, 0);
}

// ================= phase bodies (shared by fused + standalone kernels) =================

__device__ void prep_unit(int u,
                          const float* __restrict__ x,
                          const float* __restrict__ gamma,
                          const float* __restrict__ beta,
                          const float* __restrict__ W,
                          unsigned short* __restrict__ xh,
                          unsigned short* __restrict__ xl,
                          unsigned short* __restrict__ Bh,
                          unsigned short* __restrict__ Bl,
                          unsigned char* smem) {
    if (u < 1024) {
        const int row  = u * 4 + (threadIdx.x >> 6);
        const int lane = threadIdx.x & 63;
        const float* xr = x + (size_t)row * DIM_ + lane * 8;
        float4 a = *(const float4*)xr;
        float4 c = *(const float4*)(xr + 4);
        float s  = (a.x + a.y) + (a.z + a.w) + (c.x + c.y) + (c.z + c.w);
        float sq = a.x*a.x + a.y*a.y + a.z*a.z + a.w*a.w
                 + c.x*c.x + c.y*c.y + c.z*c.z + c.w*c.w;
        #pragma unroll
        for (int o = 32; o; o >>= 1) { s += __shfl_xor(s, o); sq += __shfl_xor(sq, o); }
        const float mu  = s * (1.0f / DIM_);
        const float var = sq * (1.0f / DIM_) - mu * mu;
        const float rs  = rsqrtf(var + LN_EPS);
        float4 g0 = *(const float4*)(gamma + lane * 8);
        float4 g1 = *(const float4*)(gamma + lane * 8 + 4);
        float4 b0 = *(const float4*)(beta  + lane * 8);
        float4 b1 = *(const float4*)(beta  + lane * 8 + 4);
        const float fv[8] = {
            (a.x - mu) * rs * g0.x + b0.x, (a.y - mu) * rs * g0.y + b0.y,
            (a.z - mu) * rs * g0.z + b0.z, (a.w - mu) * rs * g0.w + b0.w,
            (c.x - mu) * rs * g1.x + b1.x, (c.y - mu) * rs * g1.y + b1.y,
            (c.z - mu) * rs * g1.z + b1.z, (c.w - mu) * rs * g1.w + b1.w };
        ushort8 h, l;
        #pragma unroll
        for (int j = 0; j < 8; ++j) {
            const unsigned short hv = f2bf(fv[j]);
            h[j] = hv; l[j] = f2bf(fv[j] - bf2f(hv));
        }
        *(ushort8*)(xh + (size_t)row * DIM_ + lane * 8) = h;
        *(ushort8*)(xl + (size_t)row * DIM_ + lane * 8) = l;
    } else {
        float (*T)[65] = (float(*)[65])smem;
        const int bx = u - 1024;
        const int n0 = (bx % 24) * 64, k0 = (bx / 24) * 64;
        const int tid = threadIdx.x;
        #pragma unroll
        for (int e = 0; e < 4; ++e) {
            const int lin = e * 256 + tid;
            const int kk = lin >> 4;
            const int n4 = (lin & 15) * 4;
            float4 f = *(const float4*)(W + (size_t)(k0 + kk) * QKVW + n0 + n4);
            T[kk][n4 + 0] = f.x; T[kk][n4 + 1] = f.y;
            T[kk][n4 + 2] = f.z; T[kk][n4 + 3] = f.w;
        }
        __syncthreads();
        #pragma unroll
        for (int e = 0; e < 4; ++e) {
            const int lin = e * 256 + tid;
            const int nn = lin >> 4;
            const int kq = (lin & 15) * 4;
            ushort4 h, l;
            float f;
            f = T[kq + 0][nn]; h.x = f2bf(f); l.x = f2bf(f - bf2f(h.x));
            f = T[kq + 1][nn]; h.y = f2bf(f); l.y = f2bf(f - bf2f(h.y));
            f = T[kq + 2][nn]; h.z = f2bf(f); l.z = f2bf(f - bf2f(h.z));
            f = T[kq + 3][nn]; h.w = f2bf(f); l.w = f2bf(f - bf2f(h.w));
            *(ushort4*)(Bh + (size_t)(n0 + nn) * DIM_ + k0 + kq) = h;
            *(ushort4*)(Bl + (size_t)(n0 + nn) * DIM_ + k0 + kq) = l;
        }
        __syncthreads();
    }
}

// gemm body: BM=64 x BN=128, BK=64, XCD-swizzled; 3-pass split for Q/K, 1-pass V.
__device__ void gemm_body(int bid,
                          const unsigned short* __restrict__ Ah,
                          const unsigned short* __restrict__ Al,
                          const unsigned short* __restrict__ Bh,
                          const unsigned short* __restrict__ Bl,
                          unsigned short* __restrict__ Qh,
                          unsigned short* __restrict__ Ql,
                          unsigned short* __restrict__ Kh,
                          unsigned short* __restrict__ Kl,
                          unsigned short* __restrict__ Vt,
                          unsigned char* smem) {
    unsigned short* sAh = (unsigned short*)smem;     // 4096
    unsigned short* sAl = sAh + 64 * 64;
    unsigned short* sBh = sAl + 64 * 64;             // 8192
    unsigned short* sBl = sBh + 128 * 64;

    const int tid  = threadIdx.x;
    const int lane = tid & 63, wave = tid >> 6;
    const int wr = wave >> 1, wc = wave & 1;
    const int lg = lane >> 4, l16 = lane & 15;

    const int sb  = (bid & 7) * 96 + (bid >> 3);     // bijective: 768 = 8*96
    const int row0 = (sb / 12) * 64;
    const int col0 = (sb % 12) * 128;
    const int part = col0 >> 9;                      // 0=Q, 1=K, 2=V

    f32x4 acc[2][4] = {};

    for (int k0 = 0; k0 < DIM_; k0 += 64) {
        __syncthreads();
        #pragma unroll
        for (int e = 0; e < 2; ++e) {
            const int s0  = e * 256 + wave * 64;
            const int idx = s0 + lane;
            const int r   = idx >> 3;
            const int pb  = idx & 7;
            const int klog = pb ^ (r & 7);
            const size_t ga = (size_t)(row0 + r) * DIM_ + k0 + klog * 8;
            async_copy16(&sAh[s0 * 8], Ah + ga);
            if (part < 2) async_copy16(&sAl[s0 * 8], Al + ga);
        }
        #pragma unroll
        for (int e = 0; e < 4; ++e) {
            const int s0  = e * 256 + wave * 64;
            const int idx = s0 + lane;
            const int r   = idx >> 3;
            const int pb  = idx & 7;
            const int klog = pb ^ (r & 7);
            const size_t gb = (size_t)(col0 + r) * DIM_ + k0 + klog * 8;
            async_copy16(&sBh[s0 * 8], Bh + gb);
            if (part < 2) async_copy16(&sBl[s0 * 8], Bl + gb);
        }
        __syncthreads();   // drains vmcnt(0)

        #pragma unroll
        for (int kh = 0; kh < 2; ++kh) {
            bf16x8 ah[2], bh[4];
            #pragma unroll
            for (int mi = 0; mi < 2; ++mi) {
                const int r = wr * 32 + mi * 16 + l16;
                ah[mi] = *(const bf16x8*)&sAh[r * 64 + (((kh * 4 + lg) ^ (r & 7)) * 8)];
            }
            #pragma unroll
            for (int ni = 0; ni < 4; ++ni) {
                const int r = wc * 64 + ni * 16 + l16;
                bh[ni] = *(const bf16x8*)&sBh[r * 64 + (((kh * 4 + lg) ^ (r & 7)) * 8)];
            }
            if (part < 2) {
                bf16x8 al[2], bl[4];
                #pragma unroll
                for (int mi = 0; mi < 2; ++mi) {
                    const int r = wr * 32 + mi * 16 + l16;
                    al[mi] = *(const bf16x8*)&sAl[r * 64 + (((kh * 4 + lg) ^ (r & 7)) * 8)];
                }
                #pragma unroll
                for (int ni = 0; ni < 4; ++ni) {
                    const int r = wc * 64 + ni * 16 + l16;
                    bl[ni] = *(const bf16x8*)&sBl[r * 64 + (((kh * 4 + lg) ^ (r & 7)) * 8)];
                }
                #pragma unroll
                for (int mi = 0; mi < 2; ++mi)
                    #pragma unroll
                    for (int ni = 0; ni < 4; ++ni) {
                        acc[mi][ni] = __builtin_amdgcn_mfma_f32_16x16x32_bf16(ah[mi], bh[ni], acc[mi][ni], 0, 0, 0);
                        acc[mi][ni] = __builtin_amdgcn_mfma_f32_16x16x32_bf16(al[mi], bh[ni], acc[mi][ni], 0, 0, 0);
                        acc[mi][ni] = __builtin_amdgcn_mfma_f32_16x16x32_bf16(ah[mi], bl[ni], acc[mi][ni], 0, 0, 0);
                    }
            } else {
                #pragma unroll
                for (int mi = 0; mi < 2; ++mi)
                    #pragma unroll
                    for (int ni = 0; ni < 4; ++ni)
                        acc[mi][ni] = __builtin_amdgcn_mfma_f32_16x16x32_bf16(ah[mi], bh[ni], acc[mi][ni], 0, 0, 0);
            }
        }
    }

    const int colbase = col0 + wc * 64;
    const int head = (colbase & 511) >> 6;
    if (part < 2) {
        unsigned short* __restrict__ Ih = (part == 0) ? Qh : Kh;
        unsigned short* __restrict__ Il = (part == 0) ? Ql : Kl;
        #pragma unroll
        for (int mi = 0; mi < 2; ++mi) {
            const int rb = row0 + wr * 32 + mi * 16 + lg * 4;
            const int n  = rb & 2047;
            const size_t tbase = ((size_t)((rb >> 11) * H_ + head) * 32 + (n >> 6)) * 4096;
            #pragma unroll
            for (int ni = 0; ni < 4; ++ni) {
                const int d  = ni * 16 + l16;
                const int k8 = d >> 3;
                #pragma unroll
                for (int rr = 0; rr < 4; ++rr) {
                    const int r = (n & 63) + rr;
                    const size_t off = tbase + r * 64 + ((k8 ^ (r & 7)) * 8) + (d & 7);
                    const float v = acc[mi][ni][rr];
                    const unsigned short hv = f2bf(v);
                    Ih[off] = hv;
                    Il[off] = f2bf(v - bf2f(hv));
                }
            }
        }
    } else {
        #pragma unroll
        for (int mi = 0; mi < 2; ++mi) {
            const int rb = row0 + wr * 32 + mi * 16 + lg * 4;
            const int n  = rb & 2047;
            const size_t cbase = ((size_t)((rb >> 11) * H_ + head) * 32 + (n >> 6)) * 4096;
            const int nr = n & 63;
            #pragma unroll
            for (int ni = 0; ni < 4; ++ni) {
                const int d = ni * 16 + l16;
                const size_t off = cbase + d * 64 + (((nr >> 3) ^ (d & 7)) * 8) + (nr & 7);
                ushort4 pk;
                pk.x = f2bf(acc[mi][ni][0]); pk.y = f2bf(acc[mi][ni][1]);
                pk.z = f2bf(acc[mi][ni][2]); pk.w = f2bf(acc[mi][ni][3]);
                *(ushort4*)&Vt[off] = pk;
            }
        }
    }
}

// attn body: QBLK=64, 4 waves, XCD-swizzled (bid in [0,512))
__device__ void attn_body(int bid,
                          const unsigned short* __restrict__ Qh,
                          const unsigned short* __restrict__ Ql,
                          const unsigned short* __restrict__ Kh,
                          const unsigned short* __restrict__ Kl,
                          const unsigned short* __restrict__ Vt,
                          float* __restrict__ out,
                          unsigned char* smem) {
    unsigned short* sKh = (unsigned short*)smem;    // 4096
    unsigned short* sKl = sKh + 4096;
    unsigned short* sVt = sKl + 4096;
    unsigned short* sPb = sVt + 4096;               // 4 waves x 1024

    const int sb  = (bid & 7) * 64 + (bid >> 3);    // bijective: 512 = 8*64
    const int tile = sb & 31;
    const int h    = (sb >> 5) & 7;
    const int b    = sb >> 8;
    const int i0   = tile * 64;
    const int tid  = threadIdx.x;
    const int lane = tid & 63, wave = tid >> 6;
    const int lg   = lane >> 4, l16 = lane & 15;
    unsigned short* sP = sPb + wave * 1024;

    const size_t hb = (size_t)(b * H_ + h) * 32;

    bf16x8 qh[2], ql[2];
    {
        const int r = wave * 16 + l16;
        const size_t tb = (hb + tile) * 4096;
        #pragma unroll
        for (int kh = 0; kh < 2; ++kh) {
            const size_t off = tb + r * 64 + (((kh * 4 + lg) ^ (r & 7)) * 8);
            qh[kh] = *(const bf16x8*)(Qh + off);
            ql[kh] = *(const bf16x8*)(Ql + off);
        }
    }

    float m_run[4], l_run[4];
    f32x4 oacc[4] = {};
    #pragma unroll
    for (int r = 0; r < 4; ++r) { m_run[r] = -1e30f; l_run[r] = 0.0f; }

    #pragma unroll 1
    for (int c = 0; c < 5; ++c) {
        const int jbase = i0 - 128 + c * 64;
        if (jbase + 64 <= 0 || jbase >= N_) continue;
        __syncthreads();
        const size_t kbG = (hb + (jbase >> 6)) * 4096;
        #pragma unroll
        for (int e = 0; e < 6; ++e) {
            const int s0  = e * 256 + wave * 64;
            const int arr = s0 >> 9;
            const int w0  = (s0 & 511) * 8;
            unsigned short* dst = (arr == 0) ? sKh : (arr == 1) ? sKl : sVt;
            const unsigned short* src = (arr == 0) ? Kh : (arr == 1) ? Kl : Vt;
            async_copy16(dst + w0, src + kbG + w0 + lane * 8);
        }
        __syncthreads();   // drains vmcnt(0)

        f32x4 sacc[4] = {};
        #pragma unroll
        for (int kh = 0; kh < 2; ++kh) {
            #pragma unroll
            for (int t = 0; t < 4; ++t) {
                const int r = t * 16 + l16;
                const int off = r * 64 + ((((kh * 4 + lg)) ^ (r & 7)) * 8);
                const bf16x8 kbh = *(const bf16x8*)&sKh[off];
                const bf16x8 kbl = *(const bf16x8*)&sKl[off];
                sacc[t] = __builtin_amdgcn_mfma_f32_16x16x32_bf16(qh[kh], kbh, sacc[t], 0, 0, 0);
                sacc[t] = __builtin_amdgcn_mfma_f32_16x16x32_bf16(ql[kh], kbh, sacc[t], 0, 0, 0);
                sacc[t] = __builtin_amdgcn_mfma_f32_16x16x32_bf16(qh[kh], kbl, sacc[t], 0, 0, 0);
            }
        }

        #pragma unroll
        for (int r = 0; r < 4; ++r) {
            const int i = i0 + wave * 16 + lg * 4 + r;
            float sv[4];
            float mx = -1e30f;
            #pragma unroll
            for (int t = 0; t < 4; ++t) {
                const int j = jbase + t * 16 + l16;
                const int d = j - i;
                const bool ok = (d >= -BAND_) && (d < BAND_);
                sv[t] = ok ? sacc[t][r] : -1e30f;
                mx = fmaxf(mx, sv[t]);
            }
            #pragma unroll
            for (int o = 1; o < 16; o <<= 1) mx = fmaxf(mx, __shfl_xor(mx, o));
            const float m_new = fmaxf(m_run[r], mx);
            const float alpha = __expf(m_run[r] - m_new);
            float p[4], lc = 0.f;
            #pragma unroll
            for (int t = 0; t < 4; ++t) { p[t] = __expf(sv[t] - m_new); lc += p[t]; }
            #pragma unroll
            for (int o = 1; o < 16; o <<= 1) lc += __shfl_xor(lc, o);
            l_run[r] = l_run[r] * alpha + lc;
            m_run[r] = m_new;
            #pragma unroll
            for (int dt = 0; dt < 4; ++dt) oacc[dt][r] *= alpha;
            const int q = lg * 4 + r;
            #pragma unroll
            for (int t = 0; t < 4; ++t) {
                const int k = t * 16 + l16;
                sP[q * 64 + (((k >> 3) ^ (q & 7)) * 8) + (k & 7)] = f2bf(p[t]);
            }
        }

        #pragma unroll
        for (int kh = 0; kh < 2; ++kh) {
            const int poff = l16 * 64 + ((((kh * 4 + lg)) ^ (l16 & 7)) * 8);
            const bf16x8 pa = *(const bf16x8*)&sP[poff];
            #pragma unroll
            for (int dt = 0; dt < 4; ++dt) {
                const int rv = dt * 16 + l16;
                const int voff = rv * 64 + ((((kh * 4 + lg)) ^ (rv & 7)) * 8);
                const bf16x8 vb = *(const bf16x8*)&sVt[voff];
                oacc[dt] = __builtin_amdgcn_mfma_f32_16x16x32_bf16(pa, vb, oacc[dt], 0, 0, 0);
            }
        }
    }

    #pragma unroll
    for (int dt = 0; dt < 4; ++dt)
        #pragma unroll
        for (int r = 0; r < 4; ++r) {
            const int i = i0 + wave * 16 + lg * 4 + r;
            out[((size_t)b * N_ + i) * DIM_ + h * DH_ + dt * 16 + l16] = oacc[dt][r] / l_run[r];
        }
}

// ================= standalone kernels (fallback path) =================

__global__ __launch_bounds__(256) void prep_kernel(const float* x, const float* gamma,
                                                   const float* beta, const float* W,
                                                   unsigned short* xh, unsigned short* xl,
                                                   unsigned short* Bh, unsigned short* Bl) {
    __shared__ __attribute__((aligned(16))) unsigned char smem[16640];
    prep_unit(blockIdx.x, x, gamma, beta, W, xh, xl, Bh, Bl, smem);
}

__global__ __launch_bounds__(256) void gemm_kernel(const unsigned short* Ah, const unsigned short* Al,
                                                   const unsigned short* Bh, const unsigned short* Bl,
                                                   unsigned short* Qh, unsigned short* Ql,
                                                   unsigned short* Kh, unsigned short* Kl,
                                                   unsigned short* Vt) {
    __shared__ __attribute__((aligned(16))) unsigned char smem[49152];
    gemm_body(blockIdx.x, Ah, Al, Bh, Bl, Qh, Ql, Kh, Kl, Vt, smem);
}

__global__ __launch_bounds__(256) void attn_kernel(const unsigned short* Qh, const unsigned short* Ql,
                                                   const unsigned short* Kh, const unsigned short* Kl,
                                                   const unsigned short* Vt, float* out) {
    __shared__ __attribute__((aligned(16))) unsigned char smem[32768];
    attn_body(blockIdx.x, Qh, Ql, Kh, Kl, Vt, out, smem);
}

// ================= fused cooperative kernel =================

__global__ __launch_bounds__(256, 3) void fused_kernel(const float* x, const float* gamma,
                                                       const float* beta, const float* W,
                                                       unsigned short* xh, unsigned short* xl,
                                                       unsigned short* Bh, unsigned short* Bl,
                                                       unsigned short* Qh, unsigned short* Ql,
                                                       unsigned short* Kh, unsigned short* Kl,
                                                       unsigned short* Vt, float* out) {
    __shared__ __attribute__((aligned(16))) unsigned char smem[49152];
    const int bid = blockIdx.x;
    cg::grid_group grid = cg::this_grid();

    // phase 0: prep (1216 units over 768 blocks)
    for (int u = bid; u < 1216; u += 768)
        prep_unit(u, x, gamma, beta, W, xh, xl, Bh, Bl, smem);
    __threadfence();
    grid.sync();

    // phase 1: gemm (768 blocks)
    gemm_body(bid, xh, xl, Bh, Bl, Qh, Ql, Kh, Kl, Vt, smem);
    __threadfence();
    grid.sync();

    // phase 2: attn (first 512 blocks)
    if (bid < 512)
        attn_body(bid, Qh, Ql, Kh, Kl, Vt, out, smem);
}

extern "C" void kernel_launch(void* const* d_in, const int* in_sizes, int n_in,
                              void* d_out, int out_size, void* d_ws, size_t ws_size,
                              hipStream_t stream) {
    const float* x     = (const float*)d_in[0];
    const float* w     = (const float*)d_in[1];
    const float* gamma = (const float*)d_in[2];
    const float* beta  = (const float*)d_in[3];
    float* out = (float*)d_out;

    const size_t NTOK = (size_t)B_ * N_;             // 4096
    const size_t IMG  = (size_t)B_ * H_ * 32 * 4096; // u16 per image

    unsigned short* xnh = (unsigned short*)d_ws;
    unsigned short* xnl = xnh + NTOK * DIM_;
    unsigned short* wth = xnl + NTOK * DIM_;
    unsigned short* wtl = wth + (size_t)QKVW * DIM_;
    unsigned short* Qh  = wtl + (size_t)QKVW * DIM_;
    unsigned short* Ql  = Qh + IMG;
    unsigned short* Kh  = Ql + IMG;
    unsigned short* Kl  = Kh + IMG;
    unsigned short* Vt  = Kl + IMG;

    // deterministic host-side capability check (same result every call)
    int coop = 0, nCU = 0, maxB = 0;
    hipDeviceGetAttribute(&coop, hipDeviceAttributeCooperativeLaunch, 0);
    hipDeviceGetAttribute(&nCU, hipDeviceAttributeMultiprocessorCount, 0);
    hipOccupancyMaxActiveBlocksPerMultiprocessor(&maxB, fused_kernel, 256, 0);

    if (coop && (long)maxB * nCU >= 768) {
        void* args[] = { (void*)&x, (void*)&gamma, (void*)&beta, (void*)&w,
                         (void*)&xnh, (void*)&xnl, (void*)&wth, (void*)&wtl,
                         (void*)&Qh, (void*)&Ql, (void*)&Kh, (void*)&Kl,
                         (void*)&Vt, (void*)&out };
        if (hipLaunchCooperativeKernel((const void*)fused_kernel, dim3(768), dim3(256),
                                       args, 0, stream) == hipSuccess)
            return;
    }

    // fallback: proven 3-kernel path (R12)
    prep_kernel<<<dim3(1216), dim3(256), 0, stream>>>(x, gamma, beta, w, xnh, xnl, wth, wtl);
    gemm_kernel<<<dim3(768), dim3(256), 0, stream>>>(xnh, xnl, wth, wtl, Qh, Ql, Kh, Kl, Vt);
    attn_kernel<<<dim3(512), dim3(256), 0, stream>>>(Qh, Ql, Kh, Kl, Vt, out);
}

// Round 14
// 46.259 us; speedup vs baseline: 1.6073x; 1.6073x over previous
//
#include <hip/hip_runtime.h>
#include <hip/hip_bf16.h>

#define B_    2
#define N_    2048
#define DIM_  512
#define H_    8
#define DH_   64
#define QKVW  1536          // 3*H*DH
#define BAND_ 128
#define LN_EPS 1e-5f

typedef __attribute__((ext_vector_type(8))) short bf16x8;
typedef __attribute__((ext_vector_type(4))) float f32x4;
typedef __attribute__((ext_vector_type(8))) unsigned short ushort8;

__device__ __forceinline__ float bf2f(unsigned short u) {
    union { unsigned int i; float f; } w; w.i = ((unsigned int)u) << 16; return w.f;
}
__device__ __forceinline__ unsigned short f2bf(float f) {
    __hip_bfloat16 h = __float2bfloat16(f);
    return *reinterpret_cast<unsigned short*>(&h);
}
// async global->LDS, 16B per lane; lds base wave-uniform (HW adds lane*16)
__device__ __forceinline__ void async_copy16(void* lds, const void* g) {
    __builtin_amdgcn_global_load_lds(
        (const __attribute__((address_space(1))) unsigned int*)g,
        (__attribute__((address_space(3))) unsigned int*)lds, 16, 0, 0);
}

// ---------------- Kernel 1: fused prep = LayerNorm-split + W^T-split ----------------
__global__ __launch_bounds__(256) void prep_kernel(const float* __restrict__ x,
                                                   const float* __restrict__ gamma,
                                                   const float* __restrict__ beta,
                                                   const float* __restrict__ W,
                                                   unsigned short* __restrict__ xh,
                                                   unsigned short* __restrict__ xl,
                                                   unsigned short* __restrict__ Bh,
                                                   unsigned short* __restrict__ Bl) {
    __shared__ float T[64][65];
    if (blockIdx.x < 1024) {
        const int row  = blockIdx.x * 4 + (threadIdx.x >> 6);
        const int lane = threadIdx.x & 63;
        const float* xr = x + (size_t)row * DIM_ + lane * 8;
        float4 a = *(const float4*)xr;
        float4 c = *(const float4*)(xr + 4);
        float s  = (a.x + a.y) + (a.z + a.w) + (c.x + c.y) + (c.z + c.w);
        float sq = a.x*a.x + a.y*a.y + a.z*a.z + a.w*a.w
                 + c.x*c.x + c.y*c.y + c.z*c.z + c.w*c.w;
        #pragma unroll
        for (int o = 32; o; o >>= 1) { s += __shfl_xor(s, o); sq += __shfl_xor(sq, o); }
        const float mu  = s * (1.0f / DIM_);
        const float var = sq * (1.0f / DIM_) - mu * mu;
        const float rs  = rsqrtf(var + LN_EPS);
        float4 g0 = *(const float4*)(gamma + lane * 8);
        float4 g1 = *(const float4*)(gamma + lane * 8 + 4);
        float4 b0 = *(const float4*)(beta  + lane * 8);
        float4 b1 = *(const float4*)(beta  + lane * 8 + 4);
        const float fv[8] = {
            (a.x - mu) * rs * g0.x + b0.x, (a.y - mu) * rs * g0.y + b0.y,
            (a.z - mu) * rs * g0.z + b0.z, (a.w - mu) * rs * g0.w + b0.w,
            (c.x - mu) * rs * g1.x + b1.x, (c.y - mu) * rs * g1.y + b1.y,
            (c.z - mu) * rs * g1.z + b1.z, (c.w - mu) * rs * g1.w + b1.w };
        ushort8 h, l;
        #pragma unroll
        for (int j = 0; j < 8; ++j) {
            const unsigned short hv = f2bf(fv[j]);
            h[j] = hv; l[j] = f2bf(fv[j] - bf2f(hv));
        }
        *(ushort8*)(xh + (size_t)row * DIM_ + lane * 8) = h;
        *(ushort8*)(xl + (size_t)row * DIM_ + lane * 8) = l;
    } else {
        const int bx = blockIdx.x - 1024;
        const int n0 = (bx % 24) * 64, k0 = (bx / 24) * 64;
        const int tid = threadIdx.x;
        #pragma unroll
        for (int e = 0; e < 4; ++e) {
            const int lin = e * 256 + tid;
            const int kk = lin >> 4;
            const int n4 = (lin & 15) * 4;
            float4 f = *(const float4*)(W + (size_t)(k0 + kk) * QKVW + n0 + n4);
            T[kk][n4 + 0] = f.x; T[kk][n4 + 1] = f.y;
            T[kk][n4 + 2] = f.z; T[kk][n4 + 3] = f.w;
        }
        __syncthreads();
        #pragma unroll
        for (int e = 0; e < 4; ++e) {
            const int lin = e * 256 + tid;
            const int nn = lin >> 4;
            const int kq = (lin & 15) * 4;
            ushort4 h, l;
            float f;
            f = T[kq + 0][nn]; h.x = f2bf(f); l.x = f2bf(f - bf2f(h.x));
            f = T[kq + 1][nn]; h.y = f2bf(f); l.y = f2bf(f - bf2f(h.y));
            f = T[kq + 2][nn]; h.z = f2bf(f); l.z = f2bf(f - bf2f(h.z));
            f = T[kq + 3][nn]; h.w = f2bf(f); l.w = f2bf(f - bf2f(h.w));
            *(ushort4*)(Bh + (size_t)(n0 + nn) * DIM_ + k0 + kq) = h;
            *(ushort4*)(Bl + (size_t)(n0 + nn) * DIM_ + k0 + kq) = l;
        }
    }
}

// ---------------- Kernel 2: MFMA GEMM, BM=64 x BN=128, BK=64, XCD-swizzled ----------
// Q/K col-blocks: 3-pass split. V col-blocks (part==2): 1-pass hi*hi.
__global__ __launch_bounds__(256) void gemm_mfma(const unsigned short* __restrict__ Ah,
                                                 const unsigned short* __restrict__ Al,
                                                 const unsigned short* __restrict__ Bh,
                                                 const unsigned short* __restrict__ Bl,
                                                 unsigned short* __restrict__ Qh,
                                                 unsigned short* __restrict__ Ql,
                                                 unsigned short* __restrict__ Kh,
                                                 unsigned short* __restrict__ Kl,
                                                 unsigned short* __restrict__ Vt) {
    __shared__ __attribute__((aligned(16))) unsigned short sAh[64 * 64],  sAl[64 * 64];
    __shared__ __attribute__((aligned(16))) unsigned short sBh[128 * 64], sBl[128 * 64];
    const int tid  = threadIdx.x;
    const int lane = tid & 63, wave = tid >> 6;
    const int wr = wave >> 1, wc = wave & 1;
    const int lg = lane >> 4, l16 = lane & 15;

    const int bid = blockIdx.x;
    const int sb  = (bid & 7) * 96 + (bid >> 3);
    const int row0 = (sb / 12) * 64;
    const int col0 = (sb % 12) * 128;
    const int part = col0 >> 9;                  // 0=Q, 1=K, 2=V (block-uniform)

    f32x4 acc[2][4] = {};

    for (int k0 = 0; k0 < DIM_; k0 += 64) {
        __syncthreads();
        #pragma unroll
        for (int e = 0; e < 2; ++e) {
            const int s0  = e * 256 + wave * 64;
            const int idx = s0 + lane;
            const int r   = idx >> 3;
            const int pb  = idx & 7;
            const int klog = pb ^ (r & 7);
            const size_t ga = (size_t)(row0 + r) * DIM_ + k0 + klog * 8;
            async_copy16(&sAh[s0 * 8], Ah + ga);
            if (part < 2) async_copy16(&sAl[s0 * 8], Al + ga);
        }
        #pragma unroll
        for (int e = 0; e < 4; ++e) {
            const int s0  = e * 256 + wave * 64;
            const int idx = s0 + lane;
            const int r   = idx >> 3;
            const int pb  = idx & 7;
            const int klog = pb ^ (r & 7);
            const size_t gb = (size_t)(col0 + r) * DIM_ + k0 + klog * 8;
            async_copy16(&sBh[s0 * 8], Bh + gb);
            if (part < 2) async_copy16(&sBl[s0 * 8], Bl + gb);
        }
        __syncthreads();   // drains vmcnt(0)

        #pragma unroll
        for (int kh = 0; kh < 2; ++kh) {
            bf16x8 ah[2], bh[4];
            #pragma unroll
            for (int mi = 0; mi < 2; ++mi) {
                const int r = wr * 32 + mi * 16 + l16;
                ah[mi] = *(const bf16x8*)&sAh[r * 64 + (((kh * 4 + lg) ^ (r & 7)) * 8)];
            }
            #pragma unroll
            for (int ni = 0; ni < 4; ++ni) {
                const int r = wc * 64 + ni * 16 + l16;
                bh[ni] = *(const bf16x8*)&sBh[r * 64 + (((kh * 4 + lg) ^ (r & 7)) * 8)];
            }
            if (part < 2) {
                bf16x8 al[2], bl[4];
                #pragma unroll
                for (int mi = 0; mi < 2; ++mi) {
                    const int r = wr * 32 + mi * 16 + l16;
                    al[mi] = *(const bf16x8*)&sAl[r * 64 + (((kh * 4 + lg) ^ (r & 7)) * 8)];
                }
                #pragma unroll
                for (int ni = 0; ni < 4; ++ni) {
                    const int r = wc * 64 + ni * 16 + l16;
                    bl[ni] = *(const bf16x8*)&sBl[r * 64 + (((kh * 4 + lg) ^ (r & 7)) * 8)];
                }
                #pragma unroll
                for (int mi = 0; mi < 2; ++mi)
                    #pragma unroll
                    for (int ni = 0; ni < 4; ++ni) {
                        acc[mi][ni] = __builtin_amdgcn_mfma_f32_16x16x32_bf16(ah[mi], bh[ni], acc[mi][ni], 0, 0, 0);
                        acc[mi][ni] = __builtin_amdgcn_mfma_f32_16x16x32_bf16(al[mi], bh[ni], acc[mi][ni], 0, 0, 0);
                        acc[mi][ni] = __builtin_amdgcn_mfma_f32_16x16x32_bf16(ah[mi], bl[ni], acc[mi][ni], 0, 0, 0);
                    }
            } else {
                #pragma unroll
                for (int mi = 0; mi < 2; ++mi)
                    #pragma unroll
                    for (int ni = 0; ni < 4; ++ni)
                        acc[mi][ni] = __builtin_amdgcn_mfma_f32_16x16x32_bf16(ah[mi], bh[ni], acc[mi][ni], 0, 0, 0);
            }
        }
    }

    // ---- fused repack epilogue (C/D: col = l16, row = lg*4 + rr) ----
    const int colbase = col0 + wc * 64;
    const int head = (colbase & 511) >> 6;       // wave-uniform
    if (part < 2) {
        unsigned short* __restrict__ Ih = (part == 0) ? Qh : Kh;
        unsigned short* __restrict__ Il = (part == 0) ? Ql : Kl;
        #pragma unroll
        for (int mi = 0; mi < 2; ++mi) {
            const int rb = row0 + wr * 32 + mi * 16 + lg * 4;
            const int n  = rb & 2047;
            const size_t tbase = ((size_t)((rb >> 11) * H_ + head) * 32 + (n >> 6)) * 4096;
            #pragma unroll
            for (int ni = 0; ni < 4; ++ni) {
                const int d  = ni * 16 + l16;
                const int k8 = d >> 3;
                #pragma unroll
                for (int rr = 0; rr < 4; ++rr) {
                    const int r = (n & 63) + rr;
                    const size_t off = tbase + r * 64 + ((k8 ^ (r & 7)) * 8) + (d & 7);
                    const float v = acc[mi][ni][rr];
                    const unsigned short hv = f2bf(v);
                    Ih[off] = hv;
                    Il[off] = f2bf(v - bf2f(hv));
                }
            }
        }
    } else {
        #pragma unroll
        for (int mi = 0; mi < 2; ++mi) {
            const int rb = row0 + wr * 32 + mi * 16 + lg * 4;
            const int n  = rb & 2047;
            const size_t cbase = ((size_t)((rb >> 11) * H_ + head) * 32 + (n >> 6)) * 4096;
            const int nr = n & 63;
            #pragma unroll
            for (int ni = 0; ni < 4; ++ni) {
                const int d = ni * 16 + l16;
                const size_t off = cbase + d * 64 + (((nr >> 3) ^ (d & 7)) * 8) + (nr & 7);
                ushort4 pk;
                pk.x = f2bf(acc[mi][ni][0]); pk.y = f2bf(acc[mi][ni][1]);
                pk.z = f2bf(acc[mi][ni][2]); pk.w = f2bf(acc[mi][ni][3]);
                *(ushort4*)&Vt[off] = pk;
            }
        }
    }
}

// ---------------- Kernel 3: banded attention, MFMA, XCD-swizzled ----------------
// K (hi/lo) staged in LDS; V fragments read DIRECT from the L2-resident Vt image
// (per-XCD working set ~1.5 MB < 4 MB L2; V has no intra-wave reuse -> staging
// was pure overhead, m169 pattern).
__global__ __launch_bounds__(256) void attn_mfma(const unsigned short* __restrict__ Qh,
                                                 const unsigned short* __restrict__ Ql,
                                                 const unsigned short* __restrict__ Kh,
                                                 const unsigned short* __restrict__ Kl,
                                                 const unsigned short* __restrict__ Vt,
                                                 float* __restrict__ out) {
    const int bid = blockIdx.x;
    const int sb  = (bid & 7) * 64 + (bid >> 3);
    const int tile = sb & 31;
    const int h    = (sb >> 5) & 7;
    const int b    = sb >> 8;
    const int i0   = tile * 64;
    const int tid  = threadIdx.x;
    const int lane = tid & 63, wave = tid >> 6;
    const int lg   = lane >> 4, l16 = lane & 15;

    __shared__ __attribute__((aligned(16))) unsigned short sKh[4096], sKl[4096];
    __shared__ __attribute__((aligned(16))) unsigned short sP[4][1024];

    const size_t hb = (size_t)(b * H_ + h) * 32;

    // ---- Q fragments straight from the swizzled tile image ----
    bf16x8 qh[2], ql[2];
    {
        const int r = wave * 16 + l16;
        const size_t tb = (hb + tile) * 4096;
        #pragma unroll
        for (int kh = 0; kh < 2; ++kh) {
            const size_t off = tb + r * 64 + (((kh * 4 + lg) ^ (r & 7)) * 8);
            qh[kh] = *(const bf16x8*)(Qh + off);
            ql[kh] = *(const bf16x8*)(Ql + off);
        }
    }

    float m_run[4], l_run[4];
    f32x4 oacc[4] = {};
    #pragma unroll
    for (int r = 0; r < 4; ++r) { m_run[r] = -1e30f; l_run[r] = 0.0f; }

    #pragma unroll 1
    for (int c = 0; c < 5; ++c) {
        const int jbase = i0 - 128 + c * 64;
        if (jbase + 64 <= 0 || jbase >= N_) continue;
        __syncthreads();
        // ---- async-stage K(hi/lo) only: lds offset linear in lane ----
        const size_t kbG = (hb + (jbase >> 6)) * 4096;
        #pragma unroll
        for (int e = 0; e < 4; ++e) {
            const int s0  = e * 256 + wave * 64;        // 64-aligned run, 0..1023
            const int arr = s0 >> 9;                    // wave-uniform: 0=Kh, 1=Kl
            const int w0  = (s0 & 511) * 8;             // lds elem base
            unsigned short* dst = (arr == 0) ? sKh : sKl;
            const unsigned short* src = (arr == 0) ? Kh : Kl;
            async_copy16(dst + w0, src + kbG + w0 + lane * 8);
        }
        __syncthreads();   // drains vmcnt(0)

        // ---- S = Q K^T (3-pass split) ----
        f32x4 sacc[4] = {};
        #pragma unroll
        for (int kh = 0; kh < 2; ++kh) {
            #pragma unroll
            for (int t = 0; t < 4; ++t) {
                const int r = t * 16 + l16;
                const int off = r * 64 + ((((kh * 4 + lg)) ^ (r & 7)) * 8);
                const bf16x8 kbh = *(const bf16x8*)&sKh[off];
                const bf16x8 kbl = *(const bf16x8*)&sKl[off];
                sacc[t] = __builtin_amdgcn_mfma_f32_16x16x32_bf16(qh[kh], kbh, sacc[t], 0, 0, 0);
                sacc[t] = __builtin_amdgcn_mfma_f32_16x16x32_bf16(ql[kh], kbh, sacc[t], 0, 0, 0);
                sacc[t] = __builtin_amdgcn_mfma_f32_16x16x32_bf16(qh[kh], kbl, sacc[t], 0, 0, 0);
            }
        }

        // ---- online softmax; P -> per-wave LDS (bf16, swizzled) ----
        #pragma unroll
        for (int r = 0; r < 4; ++r) {
            const int i = i0 + wave * 16 + lg * 4 + r;
            float sv[4];
            float mx = -1e30f;
            #pragma unroll
            for (int t = 0; t < 4; ++t) {
                const int j = jbase + t * 16 + l16;
                const int d = j - i;
                const bool ok = (d >= -BAND_) && (d < BAND_);
                sv[t] = ok ? sacc[t][r] : -1e30f;
                mx = fmaxf(mx, sv[t]);
            }
            #pragma unroll
            for (int o = 1; o < 16; o <<= 1) mx = fmaxf(mx, __shfl_xor(mx, o));
            const float m_new = fmaxf(m_run[r], mx);
            const float alpha = __expf(m_run[r] - m_new);
            float p[4], lc = 0.f;
            #pragma unroll
            for (int t = 0; t < 4; ++t) { p[t] = __expf(sv[t] - m_new); lc += p[t]; }
            #pragma unroll
            for (int o = 1; o < 16; o <<= 1) lc += __shfl_xor(lc, o);
            l_run[r] = l_run[r] * alpha + lc;
            m_run[r] = m_new;
            #pragma unroll
            for (int dt = 0; dt < 4; ++dt) oacc[dt][r] *= alpha;
            const int q = lg * 4 + r;
            #pragma unroll
            for (int t = 0; t < 4; ++t) {
                const int k = t * 16 + l16;
                sP[wave][q * 64 + (((k >> 3) ^ (q & 7)) * 8) + (k & 7)] = f2bf(p[t]);
            }
        }

        // ---- O += P V (V direct from global image, L2-resident) ----
        #pragma unroll
        for (int kh = 0; kh < 2; ++kh) {
            const int poff = l16 * 64 + ((((kh * 4 + lg)) ^ (l16 & 7)) * 8);
            const bf16x8 pa = *(const bf16x8*)&sP[wave][poff];
            #pragma unroll
            for (int dt = 0; dt < 4; ++dt) {
                const int rv = dt * 16 + l16;
                const int voff = rv * 64 + ((((kh * 4 + lg)) ^ (rv & 7)) * 8);
                const bf16x8 vb = *(const bf16x8*)(Vt + kbG + voff);
                oacc[dt] = __builtin_amdgcn_mfma_f32_16x16x32_bf16(pa, vb, oacc[dt], 0, 0, 0);
            }
        }
    }

    // ---- epilogue ----
    #pragma unroll
    for (int dt = 0; dt < 4; ++dt)
        #pragma unroll
        for (int r = 0; r < 4; ++r) {
            const int i = i0 + wave * 16 + lg * 4 + r;
            out[((size_t)b * N_ + i) * DIM_ + h * DH_ + dt * 16 + l16] = oacc[dt][r] / l_run[r];
        }
}

extern "C" void kernel_launch(void* const* d_in, const int* in_sizes, int n_in,
                              void* d_out, int out_size, void* d_ws, size_t ws_size,
                              hipStream_t stream) {
    const float* x     = (const float*)d_in[0];
    const float* w     = (const float*)d_in[1];
    const float* gamma = (const float*)d_in[2];
    const float* beta  = (const float*)d_in[3];
    float* out = (float*)d_out;

    const size_t NTOK = (size_t)B_ * N_;             // 4096
    const size_t IMG  = (size_t)B_ * H_ * 32 * 4096; // u16 per image

    unsigned short* xnh = (unsigned short*)d_ws;
    unsigned short* xnl = xnh + NTOK * DIM_;
    unsigned short* wth = xnl + NTOK * DIM_;
    unsigned short* wtl = wth + (size_t)QKVW * DIM_;
    unsigned short* Qh  = wtl + (size_t)QKVW * DIM_;
    unsigned short* Ql  = Qh + IMG;
    unsigned short* Kh  = Ql + IMG;
    unsigned short* Kl  = Kh + IMG;
    unsigned short* Vt  = Kl + IMG;

    prep_kernel<<<dim3(1024 + 192), dim3(256), 0, stream>>>(x, gamma, beta, w, xnh, xnl, wth, wtl);
    gemm_mfma<<<dim3(768), dim3(256), 0, stream>>>(
        xnh, xnl, wth, wtl, Qh, Ql, Kh, Kl, Vt);
    attn_mfma<<<dim3(512), dim3(256), 0, stream>>>(Qh, Ql, Kh, Kl, Vt, out);
}